// Round 5
// baseline (486.657 us; speedup 1.0000x reference)
//
#include <hip/hip_runtime.h>
#include <hip/hip_bf16.h>

// Types
typedef short  bf16x8 __attribute__((ext_vector_type(8)));
typedef float  f32x4  __attribute__((ext_vector_type(4)));
typedef unsigned short ushort_t;

#define BK 64

#define GLD_LDS16(gp, lp) __builtin_amdgcn_global_load_lds(                 \
    (const __attribute__((address_space(1))) void*)(gp),                    \
    (__attribute__((address_space(3))) void*)(lp), 16, 0, 0)

static __device__ inline short f2bf(float x) {
    // round-to-nearest-even f32 -> bf16 bits
    unsigned u = __builtin_bit_cast(unsigned, x);
    u += 0x7fffu + ((u >> 16) & 1u);
    return (short)(u >> 16);
}

// ---------------------------------------------------------------------------
// Pre-pass: feats f32 -> bf16 (memory-bound, ~48 MB traffic)
// ---------------------------------------------------------------------------
__global__ __launch_bounds__(256)
void convert_kernel(const float* __restrict__ in, ushort_t* __restrict__ out,
                    int n)
{
    int i = (blockIdx.x * blockDim.x + threadIdx.x) * 8;
    if (i < n) {
        f32x4 a = *(const f32x4*)(in + i);
        f32x4 b = *(const f32x4*)(in + i + 4);
        bf16x8 v;
        #pragma unroll
        for (int e = 0; e < 4; ++e) {
            v[e]     = f2bf(a[e]);
            v[e + 4] = f2bf(b[e]);
        }
        *(bf16x8*)(out + i) = v;
    }
}

// ---------------------------------------------------------------------------
// Gram kernel: 64x64 tiles (T=2080 blocks -> 8.1/CU, 4 co-resident via 33KB
// LDS), 256 threads = 4 waves in 2x2 grid, each wave 32x32 (acc[2][2]).
// Double-buffered global_load_lds staging, pre-swizzled source (rule #21),
// XCD-aware bijective tile swizzle (2080 % 8 == 0).
// accbuf: [0]=S0 [1]=S1 [2]=ps [3]=pc
// ---------------------------------------------------------------------------
__global__ __launch_bounds__(256, 4)
void gram_lds64_kernel(const ushort_t* __restrict__ fb,
                       const int* __restrict__ labels,
                       const int* __restrict__ biases,
                       float* __restrict__ accbuf,
                       int N, int D)
{
    __shared__ ushort_t lds[2][2][64 * 64];   // 32 KB: [buf][A/B][tile]
    __shared__ int lab_r[64], bia_r[64], lab_c[64], bia_c[64];

    // XCD-aware bijective swizzle (grid divisible by 8)
    int t = blockIdx.x;
    int nwg = gridDim.x;
    if ((nwg & 7) == 0) t = (t & 7) * (nwg >> 3) + (t >> 3);

    // tile -> lower-triangular (r >= c)
    int r = (int)((sqrtf(8.0f * (float)t + 1.0f) - 1.0f) * 0.5f);
    while ((r + 1) * (r + 2) / 2 <= t) ++r;
    while (r * (r + 1) / 2 > t) --r;
    int c = t - r * (r + 1) / 2;
    int rowbase = r * 64, colbase = c * 64;

    int tid = threadIdx.x;
    if (tid < 64) {
        lab_r[tid] = labels[rowbase + tid];
        bia_r[tid] = biases[rowbase + tid];
    } else if (tid < 128) {
        int u = tid - 64;
        lab_c[u] = labels[colbase + u];
        bia_c[u] = biases[colbase + u];
    }

    int lane = tid & 63;
    int wid  = tid >> 6;        // 4 waves
    int wr   = wid >> 1;        // 2x2 wave grid, 32x32 each
    int wc   = wid & 1;
    int lrow = lane & 15;
    int kgrp = lane >> 4;

    // staging: per tile 512 chunks of 16B each for A and B;
    // chunk j -> row j>>3, slot j&7; source slot pre-swizzled so the LDS
    // image equals the XOR-swizzled layout reads expect (0 conflicts R2-R4).
    auto STAGE = [&](int k0, int buf) {
        ushort_t* Ab = &lds[buf][0][0];
        ushort_t* Bb = &lds[buf][1][0];
        #pragma unroll
        for (int i = 0; i < 2; ++i) {
            int j   = i * 256 + tid;           // 0..511
            int row = j >> 3;
            int kc  = (j & 7) ^ (row & 7);     // pre-swizzled source slot
            const ushort_t* ga = fb + (size_t)(rowbase + row) * D + k0 + kc * 8;
            const ushort_t* gb = fb + (size_t)(colbase + row) * D + k0 + kc * 8;
            GLD_LDS16(ga, Ab + j * 8);
            GLD_LDS16(gb, Bb + j * 8);
        }
    };

    f32x4 acc[2][2] = {};

    STAGE(0, 0);
    __syncthreads();

    int cur = 0;
    for (int k0 = 0; k0 < D; k0 += BK) {
        if (k0 + BK < D) STAGE(k0 + BK, cur ^ 1);

        const ushort_t* Ab = &lds[cur][0][0];
        const ushort_t* Bb = &lds[cur][1][0];
        #pragma unroll
        for (int kk = 0; kk < 2; ++kk) {
            bf16x8 a[2], b[2];
            #pragma unroll
            for (int m = 0; m < 2; ++m) {
                int rr = wr * 32 + m * 16 + lrow;
                int off = rr * (BK * 2) + ((kk * 64 + kgrp * 16) ^ ((rr & 7) << 4));
                a[m] = *(const bf16x8*)((const char*)Ab + off);
            }
            #pragma unroll
            for (int n = 0; n < 2; ++n) {
                int cc = wc * 32 + n * 16 + lrow;
                int off = cc * (BK * 2) + ((kk * 64 + kgrp * 16) ^ ((cc & 7) << 4));
                b[n] = *(const bf16x8*)((const char*)Bb + off);
            }
            #pragma unroll
            for (int m = 0; m < 2; ++m)
                #pragma unroll
                for (int n = 0; n < 2; ++n)
                    acc[m][n] = __builtin_amdgcn_mfma_f32_16x16x32_bf16(
                        a[m], b[n], acc[m][n], 0, 0, 0);
        }
        __syncthreads();        // drains vmcnt(0): next buffer ready
        cur ^= 1;
    }

    // ---- epilogue: clip + masks + reduce ----
    // C/D layout: col = lane&15, row = (lane>>4)*4 + reg
    float s0 = 0.f, s1 = 0.f, ps = 0.f, pc = 0.f;
    #pragma unroll
    for (int m = 0; m < 2; ++m) {
        #pragma unroll
        for (int e = 0; e < 4; ++e) {
            int li = wr * 32 + m * 16 + kgrp * 4 + e;
            int gi = rowbase + li;
            int labi = lab_r[li];
            int bi   = bia_r[li];
            #pragma unroll
            for (int n = 0; n < 2; ++n) {
                int lj = wc * 32 + n * 16 + lrow;
                int gj = colbase + lj;
                if (gi > gj) {
                    float g = acc[m][n][e];
                    g = fminf(fmaxf(g, -1.f), 1.f);
                    int bj = bia_c[lj];
                    if (bi == bj) {
                        if (bi == 0) s0 += g; else s1 += g;
                    } else if (labi == lab_c[lj] && bi < bj) {
                        ps += 1.f + g;
                        pc += 1.f;
                    }
                }
            }
        }
    }
    #pragma unroll
    for (int off = 32; off > 0; off >>= 1) {
        s0 += __shfl_down(s0, off);
        s1 += __shfl_down(s1, off);
        ps += __shfl_down(ps, off);
        pc += __shfl_down(pc, off);
    }
    if (lane == 0) {
        atomicAdd(&accbuf[0], s0);
        atomicAdd(&accbuf[1], s1);
        atomicAdd(&accbuf[2], ps);
        atomicAdd(&accbuf[3], pc);
    }
}

// ---------------------------------------------------------------------------
// Gram kernel (fallback, ws too small): fused f32->bf16 staging (R2 version,
// 128x128 tile, passed correctness)
// ---------------------------------------------------------------------------
__global__ __launch_bounds__(256, 2)
void gram_fused_kernel(const float* __restrict__ feats,
                       const int* __restrict__ labels,
                       const int* __restrict__ biases,
                       float* __restrict__ accbuf,
                       int N, int D)
{
    __shared__ ushort_t As[128 * BK];
    __shared__ ushort_t Bs[128 * BK];
    __shared__ int lab_r[128], bia_r[128], lab_c[128], bia_c[128];

    int t = blockIdx.x;
    int r = (int)((sqrtf(8.0f * (float)t + 1.0f) - 1.0f) * 0.5f);
    while ((r + 1) * (r + 2) / 2 <= t) ++r;
    while (r * (r + 1) / 2 > t) --r;
    int c = t - r * (r + 1) / 2;
    int rowbase = r * 128, colbase = c * 128;

    int tid = threadIdx.x;
    if (tid < 128) {
        lab_r[tid] = labels[rowbase + tid];
        bia_r[tid] = biases[rowbase + tid];
    } else {
        int u = tid - 128;
        lab_c[u] = labels[colbase + u];
        bia_c[u] = biases[colbase + u];
    }

    int lane = tid & 63;
    int wid  = tid >> 6;
    int wr   = wid >> 1;
    int wc   = wid & 1;
    int lrow = lane & 15;
    int kgrp = lane >> 4;

    f32x4 acc[4][4] = {};

    for (int k0 = 0; k0 < D; k0 += BK) {
        __syncthreads();
        #pragma unroll
        for (int it = 0; it < 4; ++it) {
            int wlin = tid + it * 256;
            int row  = wlin >> 3;
            int kc   = wlin & 7;
            const float* ga = feats + (size_t)(rowbase + row) * D + k0 + kc * 8;
            const float* gb = feats + (size_t)(colbase + row) * D + k0 + kc * 8;
            f32x4 a0 = *(const f32x4*)ga;
            f32x4 a1 = *(const f32x4*)(ga + 4);
            f32x4 b0 = *(const f32x4*)gb;
            f32x4 b1 = *(const f32x4*)(gb + 4);
            bf16x8 av, bv;
            #pragma unroll
            for (int e = 0; e < 4; ++e) {
                av[e]     = f2bf(a0[e]);
                av[e + 4] = f2bf(a1[e]);
                bv[e]     = f2bf(b0[e]);
                bv[e + 4] = f2bf(b1[e]);
            }
            int boff = row * (BK * 2) + ((kc * 16) ^ ((row & 7) << 4));
            *(bf16x8*)((char*)As + boff) = av;
            *(bf16x8*)((char*)Bs + boff) = bv;
        }
        __syncthreads();

        #pragma unroll
        for (int kk = 0; kk < 2; ++kk) {
            bf16x8 a[4], b[4];
            #pragma unroll
            for (int m = 0; m < 4; ++m) {
                int rr = wr * 64 + m * 16 + lrow;
                int off = rr * (BK * 2) + ((kk * 64 + kgrp * 16) ^ ((rr & 7) << 4));
                a[m] = *(const bf16x8*)((const char*)As + off);
            }
            #pragma unroll
            for (int n = 0; n < 4; ++n) {
                int cc = wc * 64 + n * 16 + lrow;
                int off = cc * (BK * 2) + ((kk * 64 + kgrp * 16) ^ ((cc & 7) << 4));
                b[n] = *(const bf16x8*)((const char*)Bs + off);
            }
            #pragma unroll
            for (int m = 0; m < 4; ++m)
                #pragma unroll
                for (int n = 0; n < 4; ++n)
                    acc[m][n] = __builtin_amdgcn_mfma_f32_16x16x32_bf16(
                        a[m], b[n], acc[m][n], 0, 0, 0);
        }
    }

    float s0 = 0.f, s1 = 0.f, ps = 0.f, pc = 0.f;
    #pragma unroll
    for (int m = 0; m < 4; ++m) {
        #pragma unroll
        for (int e = 0; e < 4; ++e) {
            int li = wr * 64 + m * 16 + kgrp * 4 + e;
            int gi = rowbase + li;
            int labi = lab_r[li];
            int bi   = bia_r[li];
            #pragma unroll
            for (int n = 0; n < 4; ++n) {
                int lj = wc * 64 + n * 16 + lrow;
                int gj = colbase + lj;
                if (gi > gj) {
                    float g = acc[m][n][e];
                    g = fminf(fmaxf(g, -1.f), 1.f);
                    int bj = bia_c[lj];
                    if (bi == bj) {
                        if (bi == 0) s0 += g; else s1 += g;
                    } else if (labi == lab_c[lj] && bi < bj) {
                        ps += 1.f + g;
                        pc += 1.f;
                    }
                }
            }
        }
    }
    #pragma unroll
    for (int off = 32; off > 0; off >>= 1) {
        s0 += __shfl_down(s0, off);
        s1 += __shfl_down(s1, off);
        ps += __shfl_down(ps, off);
        pc += __shfl_down(pc, off);
    }
    if (lane == 0) {
        atomicAdd(&accbuf[0], s0);
        atomicAdd(&accbuf[1], s1);
        atomicAdd(&accbuf[2], ps);
        atomicAdd(&accbuf[3], pc);
    }
}

// ---------------------------------------------------------------------------
// Cross-entropy + bias-class counts.  accbuf: [4]=CE sum [5]=n0 [6]=n1
// ---------------------------------------------------------------------------
__global__ __launch_bounds__(256)
void ce_count_kernel(const float* __restrict__ logits,
                     const int* __restrict__ labels,
                     const int* __restrict__ biases,
                     float* __restrict__ accbuf,
                     int N, int C)
{
    int i = blockIdx.x * blockDim.x + threadIdx.x;
    float loss = 0.f, c0 = 0.f, c1 = 0.f;
    if (i < N) {
        const float* row = logits + (size_t)i * C;
        float mx = -INFINITY;
        for (int k = 0; k < C; ++k) mx = fmaxf(mx, row[k]);
        float s = 0.f;
        for (int k = 0; k < C; ++k) s += expf(row[k] - mx);
        loss = mx + logf(s) - row[labels[i]];
        if (biases[i] == 0) c0 = 1.f; else c1 = 1.f;
    }
    #pragma unroll
    for (int off = 32; off > 0; off >>= 1) {
        loss += __shfl_down(loss, off);
        c0   += __shfl_down(c0, off);
        c1   += __shfl_down(c1, off);
    }
    if ((threadIdx.x & 63) == 0) {
        atomicAdd(&accbuf[4], loss);
        atomicAdd(&accbuf[5], c0);
        atomicAdd(&accbuf[6], c1);
    }
}

// ---------------------------------------------------------------------------
// Finalize
// ---------------------------------------------------------------------------
__global__ void finalize_kernel(const float* __restrict__ accbuf,
                                float* __restrict__ out, int N)
{
    float S0 = accbuf[0], S1 = accbuf[1], ps = accbuf[2], pc = accbuf[3];
    float ce = accbuf[4], n0 = accbuf[5], n1 = accbuf[6];
    float Mo = 0.5f * (n0 * (n0 - 1.f) + n1 * (n1 - 1.f));
    float Ro = (Mo > 0.f) ? (fabsf(S0) + fabsf(S1)) / Mo : 0.f;
    float Rp = (pc > 0.f) ? 1.f + (-0.5f * ps) / pc : 0.f;
    out[0] = ce / (float)N;
    out[1] = Ro + Rp;   // ALPHA=BETA=1
}

extern "C" void kernel_launch(void* const* d_in, const int* in_sizes, int n_in,
                              void* d_out, int out_size, void* d_ws, size_t ws_size,
                              hipStream_t stream)
{
    const float* logits = (const float*)d_in[0];
    const int*   labels = (const int*)d_in[1];
    const int*   biases = (const int*)d_in[2];
    const float* feats  = (const float*)d_in[3];

    int N = in_sizes[1];              // 4096
    int C = in_sizes[0] / N;          // 10
    int D = in_sizes[3] / N;          // 2048

    float* accbuf = (float*)d_ws;
    hipMemsetAsync(accbuf, 0, 8 * sizeof(float), stream);

    size_t need = 256 + (size_t)N * D * sizeof(ushort_t);   // 16 MB + hdr
    if (ws_size >= need) {
        ushort_t* fb = (ushort_t*)((char*)d_ws + 256);
        int nconv = N * D;
        convert_kernel<<<(nconv / 8 + 255) / 256, 256, 0, stream>>>(feats, fb,
                                                                    nconv);
        int nt = N / 64;                  // 64
        int T  = nt * (nt + 1) / 2;       // 2080 lower-tri tiles
        gram_lds64_kernel<<<T, 256, 0, stream>>>(fb, labels, biases, accbuf,
                                                 N, D);
    } else {
        int nt = N / 128;
        int T  = nt * (nt + 1) / 2;       // 528
        gram_fused_kernel<<<T, 256, 0, stream>>>(feats, labels, biases, accbuf,
                                                 N, D);
    }
    ce_count_kernel<<<(N + 255) / 256, 256, 0, stream>>>(logits, labels, biases,
                                                         accbuf, N, C);
    finalize_kernel<<<1, 1, 0, stream>>>(accbuf, (float*)d_out, N);
}

// Round 6
// 198.717 us; speedup vs baseline: 2.4490x; 2.4490x over previous
//
#include <hip/hip_runtime.h>
#include <hip/hip_bf16.h>

// Types
typedef short  bf16x8 __attribute__((ext_vector_type(8)));
typedef float  f32x4  __attribute__((ext_vector_type(4)));
typedef unsigned short ushort_t;

static __device__ inline short f2bf(float x) {
    // round-to-nearest-even f32 -> bf16 bits
    unsigned u = __builtin_bit_cast(unsigned, x);
    u += 0x7fffu + ((u >> 16) & 1u);
    return (short)(u >> 16);
}

// ---------------------------------------------------------------------------
// Pre-pass: feats f32 -> bf16 in FRAGMENT-MAJOR layout.
// Chunk id c (8 bf16 = 16B): lrow = c&15, kgrp = (c>>4)&3, Kb = (c>>6)%(D/32),
// R = (c>>6)/(D/32).  Source: row = R*16+lrow, k0 = Kb*32+kgrp*8.
// A wave's MFMA fragment for (R,Kb) is then chunks [(R*(D/32)+Kb)*64 + lane],
// i.e. ONE coalesced 1KB global_load_dwordx4 per fragment.
// Writes coalesced by construction; reads cover full 128B lines.
// ---------------------------------------------------------------------------
__global__ __launch_bounds__(256)
void convert_frag_kernel(const float* __restrict__ in,
                         ushort_t* __restrict__ out,
                         int N, int D)
{
    int c = blockIdx.x * blockDim.x + threadIdx.x;   // chunk id
    int nc = N * (D >> 3);
    if (c >= nc) return;
    int nKb  = D >> 5;
    int lrow = c & 15;
    int kgrp = (c >> 4) & 3;
    int q2   = c >> 6;
    int Kb   = q2 % nKb;
    int R    = q2 / nKb;
    int row  = R * 16 + lrow;
    int k0   = Kb * 32 + kgrp * 8;
    const float* src = in + (size_t)row * D + k0;
    f32x4 a = *(const f32x4*)src;
    f32x4 b = *(const f32x4*)(src + 4);
    bf16x8 v;
    #pragma unroll
    for (int e = 0; e < 4; ++e) {
        v[e]     = f2bf(a[e]);
        v[e + 4] = f2bf(b[e]);
    }
    *(bf16x8*)(out + (size_t)c * 8) = v;
}

// ---------------------------------------------------------------------------
// Gram kernel: wave-autonomous 64x64 tiles, NO LDS, NO barriers.
// Each wave: acc[4][4] (16 MFMA per K=32 step), fragments loaded directly
// from fragment-major fb with one coalesced 1KB load each (8 per K-step).
// 2080 tiles = 520 blocks x 4 waves; block-level XCD swizzle (520 = 8*65).
// accbuf: [0]=S0 [1]=S1 [2]=ps [3]=pc
// ---------------------------------------------------------------------------
__global__ __launch_bounds__(256, 2)
void gram_frag_kernel(const ushort_t* __restrict__ fb,
                      const int* __restrict__ labels,
                      const int* __restrict__ biases,
                      float* __restrict__ accbuf,
                      int N, int D)
{
    int nKb  = D >> 5;                 // K=32 steps
    int wid  = threadIdx.x >> 6;
    int lane = threadIdx.x & 63;
    int lrow = lane & 15;
    int kgrp = lane >> 4;

    // block-level XCD-aware bijective swizzle (grid divisible by 8)
    int bid = blockIdx.x;
    int nwg = gridDim.x;
    if ((nwg & 7) == 0) bid = (bid & 7) * (nwg >> 3) + (bid >> 3);
    int t = bid * 4 + wid;             // global tile id

    // tile -> lower-triangular (r >= c)
    int r = (int)((sqrtf(8.0f * (float)t + 1.0f) - 1.0f) * 0.5f);
    while ((r + 1) * (r + 2) / 2 <= t) ++r;
    while (r * (r + 1) / 2 > t) --r;
    int c = t - r * (r + 1) / 2;
    int rowbase = r * 64, colbase = c * 64;

    int Ra = rowbase >> 4;             // first 16-row block of row panel
    int Rb = colbase >> 4;

    const bf16x8* fbv = (const bf16x8*)fb;
    f32x4 acc[4][4] = {};

    #pragma unroll 2
    for (int Kb = 0; Kb < nKb; ++Kb) {
        bf16x8 a[4], b[4];
        #pragma unroll
        for (int m = 0; m < 4; ++m)
            a[m] = fbv[(size_t)(Ra + m) * nKb * 64 + (size_t)Kb * 64 + lane];
        #pragma unroll
        for (int n = 0; n < 4; ++n)
            b[n] = fbv[(size_t)(Rb + n) * nKb * 64 + (size_t)Kb * 64 + lane];
        #pragma unroll
        for (int m = 0; m < 4; ++m)
            #pragma unroll
            for (int n = 0; n < 4; ++n)
                acc[m][n] = __builtin_amdgcn_mfma_f32_16x16x32_bf16(
                    a[m], b[n], acc[m][n], 0, 0, 0);
    }

    // ---- epilogue: clip + masks + reduce ----
    // C/D layout: col = lane&15, row = (lane>>4)*4 + reg  (verified R2-R5)
    float s0 = 0.f, s1 = 0.f, ps = 0.f, pc = 0.f;
    #pragma unroll
    for (int n = 0; n < 4; ++n) {
        int gj = colbase + n * 16 + lrow;
        int labj = labels[gj];
        int bj   = biases[gj];
        #pragma unroll
        for (int m = 0; m < 4; ++m) {
            #pragma unroll
            for (int e = 0; e < 4; ++e) {
                int gi = rowbase + m * 16 + kgrp * 4 + e;
                if (gi > gj) {
                    float g = acc[m][n][e];
                    g = fminf(fmaxf(g, -1.f), 1.f);
                    int bi = biases[gi];
                    if (bi == bj) {
                        if (bi == 0) s0 += g; else s1 += g;
                    } else if (labels[gi] == labj && bi < bj) {
                        ps += 1.f + g;
                        pc += 1.f;
                    }
                }
            }
        }
    }
    #pragma unroll
    for (int off = 32; off > 0; off >>= 1) {
        s0 += __shfl_down(s0, off);
        s1 += __shfl_down(s1, off);
        ps += __shfl_down(ps, off);
        pc += __shfl_down(pc, off);
    }
    if (lane == 0) {
        atomicAdd(&accbuf[0], s0);
        atomicAdd(&accbuf[1], s1);
        atomicAdd(&accbuf[2], ps);
        atomicAdd(&accbuf[3], pc);
    }
}

// ---------------------------------------------------------------------------
// Gram kernel (fallback, ws too small): fused f32->bf16 staging (R2 version,
// 128x128 tile, verified correct)
// ---------------------------------------------------------------------------
__global__ __launch_bounds__(256, 2)
void gram_fused_kernel(const float* __restrict__ feats,
                       const int* __restrict__ labels,
                       const int* __restrict__ biases,
                       float* __restrict__ accbuf,
                       int N, int D)
{
    __shared__ ushort_t As[128 * 64];
    __shared__ ushort_t Bs[128 * 64];
    __shared__ int lab_r[128], bia_r[128], lab_c[128], bia_c[128];

    int t = blockIdx.x;
    int r = (int)((sqrtf(8.0f * (float)t + 1.0f) - 1.0f) * 0.5f);
    while ((r + 1) * (r + 2) / 2 <= t) ++r;
    while (r * (r + 1) / 2 > t) --r;
    int c = t - r * (r + 1) / 2;
    int rowbase = r * 128, colbase = c * 128;

    int tid = threadIdx.x;
    if (tid < 128) {
        lab_r[tid] = labels[rowbase + tid];
        bia_r[tid] = biases[rowbase + tid];
    } else {
        int u = tid - 128;
        lab_c[u] = labels[colbase + u];
        bia_c[u] = biases[colbase + u];
    }

    int lane = tid & 63;
    int wid  = tid >> 6;
    int wr   = wid >> 1;
    int wc   = wid & 1;
    int lrow = lane & 15;
    int kgrp = lane >> 4;

    f32x4 acc[4][4] = {};

    for (int k0 = 0; k0 < D; k0 += 64) {
        __syncthreads();
        #pragma unroll
        for (int it = 0; it < 4; ++it) {
            int wlin = tid + it * 256;
            int row  = wlin >> 3;
            int kc   = wlin & 7;
            const float* ga = feats + (size_t)(rowbase + row) * D + k0 + kc * 8;
            const float* gb = feats + (size_t)(colbase + row) * D + k0 + kc * 8;
            f32x4 a0 = *(const f32x4*)ga;
            f32x4 a1 = *(const f32x4*)(ga + 4);
            f32x4 b0 = *(const f32x4*)gb;
            f32x4 b1 = *(const f32x4*)(gb + 4);
            bf16x8 av, bv;
            #pragma unroll
            for (int e = 0; e < 4; ++e) {
                av[e]     = f2bf(a0[e]);
                av[e + 4] = f2bf(a1[e]);
                bv[e]     = f2bf(b0[e]);
                bv[e + 4] = f2bf(b1[e]);
            }
            int boff = row * 128 + ((kc * 16) ^ ((row & 7) << 4));
            *(bf16x8*)((char*)As + boff) = av;
            *(bf16x8*)((char*)Bs + boff) = bv;
        }
        __syncthreads();

        #pragma unroll
        for (int kk = 0; kk < 2; ++kk) {
            bf16x8 a[4], b[4];
            #pragma unroll
            for (int m = 0; m < 4; ++m) {
                int rr = wr * 64 + m * 16 + lrow;
                int off = rr * 128 + ((kk * 64 + kgrp * 16) ^ ((rr & 7) << 4));
                a[m] = *(const bf16x8*)((const char*)As + off);
            }
            #pragma unroll
            for (int n = 0; n < 4; ++n) {
                int cc = wc * 64 + n * 16 + lrow;
                int off = cc * 128 + ((kk * 64 + kgrp * 16) ^ ((cc & 7) << 4));
                b[n] = *(const bf16x8*)((const char*)Bs + off);
            }
            #pragma unroll
            for (int m = 0; m < 4; ++m)
                #pragma unroll
                for (int n = 0; n < 4; ++n)
                    acc[m][n] = __builtin_amdgcn_mfma_f32_16x16x32_bf16(
                        a[m], b[n], acc[m][n], 0, 0, 0);
        }
    }

    float s0 = 0.f, s1 = 0.f, ps = 0.f, pc = 0.f;
    #pragma unroll
    for (int m = 0; m < 4; ++m) {
        #pragma unroll
        for (int e = 0; e < 4; ++e) {
            int li = wr * 64 + m * 16 + kgrp * 4 + e;
            int gi = rowbase + li;
            int labi = lab_r[li];
            int bi   = bia_r[li];
            #pragma unroll
            for (int n = 0; n < 4; ++n) {
                int lj = wc * 64 + n * 16 + lrow;
                int gj = colbase + lj;
                if (gi > gj) {
                    float g = acc[m][n][e];
                    g = fminf(fmaxf(g, -1.f), 1.f);
                    int bj = bia_c[lj];
                    if (bi == bj) {
                        if (bi == 0) s0 += g; else s1 += g;
                    } else if (labi == lab_c[lj] && bi < bj) {
                        ps += 1.f + g;
                        pc += 1.f;
                    }
                }
            }
        }
    }
    #pragma unroll
    for (int off = 32; off > 0; off >>= 1) {
        s0 += __shfl_down(s0, off);
        s1 += __shfl_down(s1, off);
        ps += __shfl_down(ps, off);
        pc += __shfl_down(pc, off);
    }
    if (lane == 0) {
        atomicAdd(&accbuf[0], s0);
        atomicAdd(&accbuf[1], s1);
        atomicAdd(&accbuf[2], ps);
        atomicAdd(&accbuf[3], pc);
    }
}

// ---------------------------------------------------------------------------
// Cross-entropy + bias-class counts.  accbuf: [4]=CE sum [5]=n0 [6]=n1
// ---------------------------------------------------------------------------
__global__ __launch_bounds__(256)
void ce_count_kernel(const float* __restrict__ logits,
                     const int* __restrict__ labels,
                     const int* __restrict__ biases,
                     float* __restrict__ accbuf,
                     int N, int C)
{
    int i = blockIdx.x * blockDim.x + threadIdx.x;
    float loss = 0.f, c0 = 0.f, c1 = 0.f;
    if (i < N) {
        const float* row = logits + (size_t)i * C;
        float mx = -INFINITY;
        for (int k = 0; k < C; ++k) mx = fmaxf(mx, row[k]);
        float s = 0.f;
        for (int k = 0; k < C; ++k) s += expf(row[k] - mx);
        loss = mx + logf(s) - row[labels[i]];
        if (biases[i] == 0) c0 = 1.f; else c1 = 1.f;
    }
    #pragma unroll
    for (int off = 32; off > 0; off >>= 1) {
        loss += __shfl_down(loss, off);
        c0   += __shfl_down(c0, off);
        c1   += __shfl_down(c1, off);
    }
    if ((threadIdx.x & 63) == 0) {
        atomicAdd(&accbuf[4], loss);
        atomicAdd(&accbuf[5], c0);
        atomicAdd(&accbuf[6], c1);
    }
}

// ---------------------------------------------------------------------------
// Finalize
// ---------------------------------------------------------------------------
__global__ void finalize_kernel(const float* __restrict__ accbuf,
                                float* __restrict__ out, int N)
{
    float S0 = accbuf[0], S1 = accbuf[1], ps = accbuf[2], pc = accbuf[3];
    float ce = accbuf[4], n0 = accbuf[5], n1 = accbuf[6];
    float Mo = 0.5f * (n0 * (n0 - 1.f) + n1 * (n1 - 1.f));
    float Ro = (Mo > 0.f) ? (fabsf(S0) + fabsf(S1)) / Mo : 0.f;
    float Rp = (pc > 0.f) ? 1.f + (-0.5f * ps) / pc : 0.f;
    out[0] = ce / (float)N;
    out[1] = Ro + Rp;   // ALPHA=BETA=1
}

extern "C" void kernel_launch(void* const* d_in, const int* in_sizes, int n_in,
                              void* d_out, int out_size, void* d_ws, size_t ws_size,
                              hipStream_t stream)
{
    const float* logits = (const float*)d_in[0];
    const int*   labels = (const int*)d_in[1];
    const int*   biases = (const int*)d_in[2];
    const float* feats  = (const float*)d_in[3];

    int N = in_sizes[1];              // 4096
    int C = in_sizes[0] / N;          // 10
    int D = in_sizes[3] / N;          // 2048

    float* accbuf = (float*)d_ws;
    hipMemsetAsync(accbuf, 0, 8 * sizeof(float), stream);

    size_t need = 256 + (size_t)N * D * sizeof(ushort_t);   // 16 MB + hdr
    if (ws_size >= need) {
        ushort_t* fb = (ushort_t*)((char*)d_ws + 256);
        int nc = N * (D >> 3);
        convert_frag_kernel<<<(nc + 255) / 256, 256, 0, stream>>>(feats, fb,
                                                                  N, D);
        int nt = N / 64;                  // 64
        int T  = nt * (nt + 1) / 2;       // 2080 wave-tiles
        gram_frag_kernel<<<T / 4, 256, 0, stream>>>(fb, labels, biases,
                                                    accbuf, N, D);
    } else {
        int nt = N / 128;
        int T  = nt * (nt + 1) / 2;       // 528
        gram_fused_kernel<<<T, 256, 0, stream>>>(feats, labels, biases, accbuf,
                                                 N, D);
    }
    ce_count_kernel<<<(N + 255) / 256, 256, 0, stream>>>(logits, labels, biases,
                                                         accbuf, N, C);
    finalize_kernel<<<1, 1, 0, stream>>>(accbuf, (float*)d_out, N);
}

// Round 7
// 193.540 us; speedup vs baseline: 2.5145x; 1.0267x over previous
//
#include <hip/hip_runtime.h>
#include <hip/hip_bf16.h>

// Types
typedef short  bf16x8 __attribute__((ext_vector_type(8)));
typedef float  f32x4  __attribute__((ext_vector_type(4)));
typedef unsigned short ushort_t;

static __device__ inline short f2bf(float x) {
    // round-to-nearest-even f32 -> bf16 bits
    unsigned u = __builtin_bit_cast(unsigned, x);
    u += 0x7fffu + ((u >> 16) & 1u);
    return (short)(u >> 16);
}

// ---------------------------------------------------------------------------
// Pre-pass: feats f32 -> bf16 in FRAGMENT-MAJOR layout.
// Chunk id c (8 bf16 = 16B): lrow = c&15, kgrp = (c>>4)&3, Kb = (c>>6)%(D/32),
// R = (c>>6)/(D/32).  Source: row = R*16+lrow, k0 = Kb*32+kgrp*8.
// A wave's MFMA fragment for (R,Kb) is then chunks [(R*(D/32)+Kb)*64 + lane],
// i.e. ONE coalesced 1KB global_load_dwordx4 per fragment.
// ---------------------------------------------------------------------------
__global__ __launch_bounds__(256)
void convert_frag_kernel(const float* __restrict__ in,
                         ushort_t* __restrict__ out,
                         int N, int D)
{
    int c = blockIdx.x * blockDim.x + threadIdx.x;   // chunk id
    int nc = N * (D >> 3);
    if (c >= nc) return;
    int nKb  = D >> 5;
    int lrow = c & 15;
    int kgrp = (c >> 4) & 3;
    int q2   = c >> 6;
    int Kb   = q2 % nKb;
    int R    = q2 / nKb;
    int row  = R * 16 + lrow;
    int k0   = Kb * 32 + kgrp * 8;
    const float* src = in + (size_t)row * D + k0;
    f32x4 a = *(const f32x4*)src;
    f32x4 b = *(const f32x4*)(src + 4);
    bf16x8 v;
    #pragma unroll
    for (int e = 0; e < 4; ++e) {
        v[e]     = f2bf(a[e]);
        v[e + 4] = f2bf(b[e]);
    }
    *(bf16x8*)(out + (size_t)c * 8) = v;
}

// ---------------------------------------------------------------------------
// Gram kernel, L2-banded schedule (N==4096 only): 528 blocks, block b runs
// on XCD x=b&7 (round-robin heuristic). XCD x owns half-bands x and 15-x
// (tile-rows {2x,2x+1} and {30-2x,31-2x}): 4x+3 + 63-4x = 66 tiles each,
// perfectly balanced, and its A-rows (4 x 128 rows = 2 MB bf16) stay
// L2-resident. Within a half-band, tiles are ordered (r0,c),(r0+1,c) so
// concurrent blocks share B-panels in L2 (~2x B reuse).
// Block = 128x128 tile, 4 barrier-free 64x64 wave-quadrants (R6 body).
// accbuf: [0]=S0 [1]=S1 [2]=ps [3]=pc
// ---------------------------------------------------------------------------
__global__ __launch_bounds__(256, 2)
void gram_band_kernel(const ushort_t* __restrict__ fb,
                      const int* __restrict__ labels,
                      const int* __restrict__ biases,
                      float* __restrict__ accbuf,
                      int N, int D)
{
    int nKb  = D >> 5;                 // K=32 steps
    int wid  = threadIdx.x >> 6;
    int lane = threadIdx.x & 63;
    int wr   = wid >> 1;               // quadrant row (0/1)
    int wc   = wid & 1;                // quadrant col (0/1)
    int lrow = lane & 15;
    int kgrp = lane >> 4;

    // ---- block -> (tile r, tile c) via XCD band mapping ----
    int x = blockIdx.x & 7;            // XCD (round-robin heuristic)
    int s = blockIdx.x >> 3;           // slot 0..65 within XCD
    int r, c;
    int n0 = 4 * x + 3;                // tiles in half-band h0 = x
    if (s < n0) {
        if (s == n0 - 1)      { r = 2 * x + 1;      c = 2 * x + 1; }
        else                  { r = 2 * x + (s & 1); c = s >> 1;   }
    } else {
        int s1    = s - n0;
        int rows0 = 30 - 2 * x;        // first row of half-band h1 = 15-x
        if (s1 == 2 * (rows0 + 1)) { r = rows0 + 1;        c = rows0 + 1; }
        else                       { r = rows0 + (s1 & 1); c = s1 >> 1;   }
    }

    int rowbase = r * 128 + wr * 64;
    int colbase = c * 128 + wc * 64;

    int Ra = rowbase >> 4;             // first 16-row block of row panel
    int Rb = colbase >> 4;

    const bf16x8* fbv = (const bf16x8*)fb;
    f32x4 acc[4][4] = {};

    #pragma unroll 2
    for (int Kb = 0; Kb < nKb; ++Kb) {
        bf16x8 a[4], b[4];
        #pragma unroll
        for (int m = 0; m < 4; ++m)
            a[m] = fbv[(size_t)(Ra + m) * nKb * 64 + (size_t)Kb * 64 + lane];
        #pragma unroll
        for (int n = 0; n < 4; ++n)
            b[n] = fbv[(size_t)(Rb + n) * nKb * 64 + (size_t)Kb * 64 + lane];
        #pragma unroll
        for (int m = 0; m < 4; ++m)
            #pragma unroll
            for (int n = 0; n < 4; ++n)
                acc[m][n] = __builtin_amdgcn_mfma_f32_16x16x32_bf16(
                    a[m], b[n], acc[m][n], 0, 0, 0);
    }

    // ---- epilogue: clip + masks + reduce ----
    // C/D layout: col = lane&15, row = (lane>>4)*4 + reg  (verified R2-R6)
    float s0 = 0.f, s1 = 0.f, ps = 0.f, pc = 0.f;
    #pragma unroll
    for (int n = 0; n < 4; ++n) {
        int gj = colbase + n * 16 + lrow;
        int labj = labels[gj];
        int bj   = biases[gj];
        #pragma unroll
        for (int m = 0; m < 4; ++m) {
            #pragma unroll
            for (int e = 0; e < 4; ++e) {
                int gi = rowbase + m * 16 + kgrp * 4 + e;
                if (gi > gj) {
                    float g = acc[m][n][e];
                    g = fminf(fmaxf(g, -1.f), 1.f);
                    int bi = biases[gi];
                    if (bi == bj) {
                        if (bi == 0) s0 += g; else s1 += g;
                    } else if (labels[gi] == labj && bi < bj) {
                        ps += 1.f + g;
                        pc += 1.f;
                    }
                }
            }
        }
    }
    #pragma unroll
    for (int off = 32; off > 0; off >>= 1) {
        s0 += __shfl_down(s0, off);
        s1 += __shfl_down(s1, off);
        ps += __shfl_down(ps, off);
        pc += __shfl_down(pc, off);
    }
    if (lane == 0) {
        atomicAdd(&accbuf[0], s0);
        atomicAdd(&accbuf[1], s1);
        atomicAdd(&accbuf[2], ps);
        atomicAdd(&accbuf[3], pc);
    }
}

// ---------------------------------------------------------------------------
// Gram kernel (generic fallback, any N%64==0): R6 wave-autonomous version
// ---------------------------------------------------------------------------
__global__ __launch_bounds__(256, 2)
void gram_frag_kernel(const ushort_t* __restrict__ fb,
                      const int* __restrict__ labels,
                      const int* __restrict__ biases,
                      float* __restrict__ accbuf,
                      int N, int D)
{
    int nKb  = D >> 5;
    int wid  = threadIdx.x >> 6;
    int lane = threadIdx.x & 63;
    int lrow = lane & 15;
    int kgrp = lane >> 4;

    int bid = blockIdx.x;
    int nwg = gridDim.x;
    if ((nwg & 7) == 0) bid = (bid & 7) * (nwg >> 3) + (bid >> 3);
    int t = bid * 4 + wid;

    int r = (int)((sqrtf(8.0f * (float)t + 1.0f) - 1.0f) * 0.5f);
    while ((r + 1) * (r + 2) / 2 <= t) ++r;
    while (r * (r + 1) / 2 > t) --r;
    int c = t - r * (r + 1) / 2;
    int rowbase = r * 64, colbase = c * 64;

    int Ra = rowbase >> 4;
    int Rb = colbase >> 4;

    const bf16x8* fbv = (const bf16x8*)fb;
    f32x4 acc[4][4] = {};

    #pragma unroll 2
    for (int Kb = 0; Kb < nKb; ++Kb) {
        bf16x8 a[4], b[4];
        #pragma unroll
        for (int m = 0; m < 4; ++m)
            a[m] = fbv[(size_t)(Ra + m) * nKb * 64 + (size_t)Kb * 64 + lane];
        #pragma unroll
        for (int n = 0; n < 4; ++n)
            b[n] = fbv[(size_t)(Rb + n) * nKb * 64 + (size_t)Kb * 64 + lane];
        #pragma unroll
        for (int m = 0; m < 4; ++m)
            #pragma unroll
            for (int n = 0; n < 4; ++n)
                acc[m][n] = __builtin_amdgcn_mfma_f32_16x16x32_bf16(
                    a[m], b[n], acc[m][n], 0, 0, 0);
    }

    float s0 = 0.f, s1 = 0.f, ps = 0.f, pc = 0.f;
    #pragma unroll
    for (int n = 0; n < 4; ++n) {
        int gj = colbase + n * 16 + lrow;
        int labj = labels[gj];
        int bj   = biases[gj];
        #pragma unroll
        for (int m = 0; m < 4; ++m) {
            #pragma unroll
            for (int e = 0; e < 4; ++e) {
                int gi = rowbase + m * 16 + kgrp * 4 + e;
                if (gi > gj) {
                    float g = acc[m][n][e];
                    g = fminf(fmaxf(g, -1.f), 1.f);
                    int bi = biases[gi];
                    if (bi == bj) {
                        if (bi == 0) s0 += g; else s1 += g;
                    } else if (labels[gi] == labj && bi < bj) {
                        ps += 1.f + g;
                        pc += 1.f;
                    }
                }
            }
        }
    }
    #pragma unroll
    for (int off = 32; off > 0; off >>= 1) {
        s0 += __shfl_down(s0, off);
        s1 += __shfl_down(s1, off);
        ps += __shfl_down(ps, off);
        pc += __shfl_down(pc, off);
    }
    if (lane == 0) {
        atomicAdd(&accbuf[0], s0);
        atomicAdd(&accbuf[1], s1);
        atomicAdd(&accbuf[2], ps);
        atomicAdd(&accbuf[3], pc);
    }
}

// ---------------------------------------------------------------------------
// Cross-entropy + bias-class counts.  accbuf: [4]=CE sum [5]=n0 [6]=n1
// ---------------------------------------------------------------------------
__global__ __launch_bounds__(256)
void ce_count_kernel(const float* __restrict__ logits,
                     const int* __restrict__ labels,
                     const int* __restrict__ biases,
                     float* __restrict__ accbuf,
                     int N, int C)
{
    int i = blockIdx.x * blockDim.x + threadIdx.x;
    float loss = 0.f, c0 = 0.f, c1 = 0.f;
    if (i < N) {
        const float* row = logits + (size_t)i * C;
        float mx = -INFINITY;
        for (int k = 0; k < C; ++k) mx = fmaxf(mx, row[k]);
        float s = 0.f;
        for (int k = 0; k < C; ++k) s += expf(row[k] - mx);
        loss = mx + logf(s) - row[labels[i]];
        if (biases[i] == 0) c0 = 1.f; else c1 = 1.f;
    }
    #pragma unroll
    for (int off = 32; off > 0; off >>= 1) {
        loss += __shfl_down(loss, off);
        c0   += __shfl_down(c0, off);
        c1   += __shfl_down(c1, off);
    }
    if ((threadIdx.x & 63) == 0) {
        atomicAdd(&accbuf[4], loss);
        atomicAdd(&accbuf[5], c0);
        atomicAdd(&accbuf[6], c1);
    }
}

// ---------------------------------------------------------------------------
// Finalize
// ---------------------------------------------------------------------------
__global__ void finalize_kernel(const float* __restrict__ accbuf,
                                float* __restrict__ out, int N)
{
    float S0 = accbuf[0], S1 = accbuf[1], ps = accbuf[2], pc = accbuf[3];
    float ce = accbuf[4], n0 = accbuf[5], n1 = accbuf[6];
    float Mo = 0.5f * (n0 * (n0 - 1.f) + n1 * (n1 - 1.f));
    float Ro = (Mo > 0.f) ? (fabsf(S0) + fabsf(S1)) / Mo : 0.f;
    float Rp = (pc > 0.f) ? 1.f + (-0.5f * ps) / pc : 0.f;
    out[0] = ce / (float)N;
    out[1] = Ro + Rp;   // ALPHA=BETA=1
}

extern "C" void kernel_launch(void* const* d_in, const int* in_sizes, int n_in,
                              void* d_out, int out_size, void* d_ws, size_t ws_size,
                              hipStream_t stream)
{
    const float* logits = (const float*)d_in[0];
    const int*   labels = (const int*)d_in[1];
    const int*   biases = (const int*)d_in[2];
    const float* feats  = (const float*)d_in[3];

    int N = in_sizes[1];              // 4096
    int C = in_sizes[0] / N;          // 10
    int D = in_sizes[3] / N;          // 2048

    float* accbuf = (float*)d_ws;
    hipMemsetAsync(accbuf, 0, 8 * sizeof(float), stream);

    ushort_t* fb = (ushort_t*)((char*)d_ws + 256);
    int nc = N * (D >> 3);
    convert_frag_kernel<<<(nc + 255) / 256, 256, 0, stream>>>(feats, fb, N, D);

    if (N == 4096) {
        // L2-banded schedule: 528 blocks = 8 XCDs x 66 slots
        gram_band_kernel<<<528, 256, 0, stream>>>(fb, labels, biases, accbuf,
                                                  N, D);
    } else {
        int nt = N / 64;
        int T  = nt * (nt + 1) / 2;
        gram_frag_kernel<<<T / 4, 256, 0, stream>>>(fb, labels, biases,
                                                    accbuf, N, D);
    }
    ce_count_kernel<<<(N + 255) / 256, 256, 0, stream>>>(logits, labels, biases,
                                                         accbuf, N, C);
    finalize_kernel<<<1, 1, 0, stream>>>(accbuf, (float*)d_out, N);
}

// Round 8
// 188.977 us; speedup vs baseline: 2.5752x; 1.0241x over previous
//
#include <hip/hip_runtime.h>
#include <hip/hip_bf16.h>

// Types
typedef float f32x4 __attribute__((ext_vector_type(4)));
typedef unsigned int uint2v __attribute__((ext_vector_type(2)));
typedef unsigned short ushort_t;

// ---------------------------------------------------------------------------
// Pre-pass: feats f32 -> fp8 e4m3 (OCP) in FRAGMENT-MAJOR layout.
// Chunk id c (8 fp8 = 8B): lrow = c&15, kgrp = (c>>4)&3, Kb = (c>>6)%(D/32),
// R = (c>>6)/(D/32).  Source: row = R*16+lrow, k0 = Kb*32+kgrp*8.
// A wave's MFMA A/B fragment for (R,Kb) is chunks [(R*(D/32)+Kb)*64 + lane]:
// ONE coalesced 512B global_load_dwordx2 per fragment.
// ---------------------------------------------------------------------------
__global__ __launch_bounds__(256)
void convert_frag8_kernel(const float* __restrict__ in,
                          unsigned char* __restrict__ out,
                          int N, int D)
{
    int c = blockIdx.x * blockDim.x + threadIdx.x;   // chunk id
    int nc = N * (D >> 3);
    if (c >= nc) return;
    int nKb  = D >> 5;
    int lrow = c & 15;
    int kgrp = (c >> 4) & 3;
    int q2   = c >> 6;
    int Kb   = q2 % nKb;
    int R    = q2 / nKb;
    int row  = R * 16 + lrow;
    int k0   = Kb * 32 + kgrp * 8;
    const float* src = in + (size_t)row * D + k0;
    f32x4 a = *(const f32x4*)src;
    f32x4 b = *(const f32x4*)(src + 4);
    // HW pack: 2 f32 -> 2 fp8 bytes into low/high word halves
    unsigned lo = __builtin_amdgcn_cvt_pk_fp8_f32(a[0], a[1], 0, 0);
    lo = __builtin_amdgcn_cvt_pk_fp8_f32(a[2], a[3], lo, 1);
    unsigned hi = __builtin_amdgcn_cvt_pk_fp8_f32(b[0], b[1], 0, 0);
    hi = __builtin_amdgcn_cvt_pk_fp8_f32(b[2], b[3], hi, 1);
    uint2v v = {lo, hi};
    *(uint2v*)(out + (size_t)c * 8) = v;
}

// ---------------------------------------------------------------------------
// Gram kernel, L2-banded schedule (N==4096): 528 blocks; XCD x=b&7 owns
// half-bands x and 15-x (66 tiles each, A-rows L2-resident). Block =
// 128x128 tile as 4 barrier-free 64x64 wave-quadrants. fp8 fragments:
// 8 loads x 512B per K=32 step, 16 MFMA (fp8 rate == bf16 rate).
// accbuf: [0]=S0 [1]=S1 [2]=ps [3]=pc
// ---------------------------------------------------------------------------
__global__ __launch_bounds__(256, 2)
void gram_band8_kernel(const unsigned char* __restrict__ fb,
                       const int* __restrict__ labels,
                       const int* __restrict__ biases,
                       float* __restrict__ accbuf,
                       int N, int D)
{
    int nKb  = D >> 5;                 // K=32 steps
    int wid  = threadIdx.x >> 6;
    int lane = threadIdx.x & 63;
    int wr   = wid >> 1;               // quadrant row (0/1)
    int wc   = wid & 1;                // quadrant col (0/1)
    int lrow = lane & 15;
    int kgrp = lane >> 4;

    // ---- block -> (tile r, tile c) via XCD band mapping (R7, verified) ----
    int x = blockIdx.x & 7;
    int s = blockIdx.x >> 3;
    int r, c;
    int n0 = 4 * x + 3;
    if (s < n0) {
        if (s == n0 - 1)      { r = 2 * x + 1;       c = 2 * x + 1; }
        else                  { r = 2 * x + (s & 1); c = s >> 1;    }
    } else {
        int s1    = s - n0;
        int rows0 = 30 - 2 * x;
        if (s1 == 2 * (rows0 + 1)) { r = rows0 + 1;        c = rows0 + 1; }
        else                       { r = rows0 + (s1 & 1); c = s1 >> 1;   }
    }

    int rowbase = r * 128 + wr * 64;
    int colbase = c * 128 + wc * 64;

    int Ra = rowbase >> 4;
    int Rb = colbase >> 4;

    const unsigned long* fbv = (const unsigned long*)fb;
    const unsigned long* pa[4];
    const unsigned long* pb[4];
    #pragma unroll
    for (int m = 0; m < 4; ++m) {
        pa[m] = fbv + (size_t)(Ra + m) * nKb * 64 + lane;
        pb[m] = fbv + (size_t)(Rb + m) * nKb * 64 + lane;
    }

    f32x4 acc[4][4] = {};

    #pragma unroll 4
    for (int Kb = 0; Kb < nKb; ++Kb) {
        long a[4], b[4];
        #pragma unroll
        for (int m = 0; m < 4; ++m) a[m] = (long)pa[m][(size_t)Kb * 64];
        #pragma unroll
        for (int n = 0; n < 4; ++n) b[n] = (long)pb[n][(size_t)Kb * 64];
        #pragma unroll
        for (int m = 0; m < 4; ++m)
            #pragma unroll
            for (int n = 0; n < 4; ++n)
                acc[m][n] = __builtin_amdgcn_mfma_f32_16x16x32_fp8_fp8(
                    a[m], b[n], acc[m][n], 0, 0, 0);
    }

    // ---- epilogue: clip + masks + reduce ----
    // C/D layout: col = lane&15, row = (lane>>4)*4 + reg (shape-determined,
    // dtype-independent; verified R2-R7)
    float s0 = 0.f, s1 = 0.f, ps = 0.f, pc = 0.f;
    #pragma unroll
    for (int n = 0; n < 4; ++n) {
        int gj = colbase + n * 16 + lrow;
        int labj = labels[gj];
        int bj   = biases[gj];
        #pragma unroll
        for (int m = 0; m < 4; ++m) {
            #pragma unroll
            for (int e = 0; e < 4; ++e) {
                int gi = rowbase + m * 16 + kgrp * 4 + e;
                if (gi > gj) {
                    float g = acc[m][n][e];
                    g = fminf(fmaxf(g, -1.f), 1.f);
                    int bi = biases[gi];
                    if (bi == bj) {
                        if (bi == 0) s0 += g; else s1 += g;
                    } else if (labels[gi] == labj && bi < bj) {
                        ps += 1.f + g;
                        pc += 1.f;
                    }
                }
            }
        }
    }
    #pragma unroll
    for (int off = 32; off > 0; off >>= 1) {
        s0 += __shfl_down(s0, off);
        s1 += __shfl_down(s1, off);
        ps += __shfl_down(ps, off);
        pc += __shfl_down(pc, off);
    }
    if (lane == 0) {
        atomicAdd(&accbuf[0], s0);
        atomicAdd(&accbuf[1], s1);
        atomicAdd(&accbuf[2], ps);
        atomicAdd(&accbuf[3], pc);
    }
}

// ---------------------------------------------------------------------------
// Gram kernel (generic fallback, any N%64==0): wave-autonomous fp8 version
// ---------------------------------------------------------------------------
__global__ __launch_bounds__(256, 2)
void gram_frag8_kernel(const unsigned char* __restrict__ fb,
                       const int* __restrict__ labels,
                       const int* __restrict__ biases,
                       float* __restrict__ accbuf,
                       int N, int D)
{
    int nKb  = D >> 5;
    int wid  = threadIdx.x >> 6;
    int lane = threadIdx.x & 63;
    int lrow = lane & 15;
    int kgrp = lane >> 4;

    int bid = blockIdx.x;
    int nwg = gridDim.x;
    if ((nwg & 7) == 0) bid = (bid & 7) * (nwg >> 3) + (bid >> 3);
    int t = bid * 4 + wid;

    int r = (int)((sqrtf(8.0f * (float)t + 1.0f) - 1.0f) * 0.5f);
    while ((r + 1) * (r + 2) / 2 <= t) ++r;
    while (r * (r + 1) / 2 > t) --r;
    int c = t - r * (r + 1) / 2;
    int rowbase = r * 64, colbase = c * 64;

    int Ra = rowbase >> 4;
    int Rb = colbase >> 4;

    const unsigned long* fbv = (const unsigned long*)fb;
    f32x4 acc[4][4] = {};

    #pragma unroll 4
    for (int Kb = 0; Kb < nKb; ++Kb) {
        long a[4], b[4];
        #pragma unroll
        for (int m = 0; m < 4; ++m)
            a[m] = (long)fbv[(size_t)(Ra + m) * nKb * 64 + (size_t)Kb * 64 + lane];
        #pragma unroll
        for (int n = 0; n < 4; ++n)
            b[n] = (long)fbv[(size_t)(Rb + n) * nKb * 64 + (size_t)Kb * 64 + lane];
        #pragma unroll
        for (int m = 0; m < 4; ++m)
            #pragma unroll
            for (int n = 0; n < 4; ++n)
                acc[m][n] = __builtin_amdgcn_mfma_f32_16x16x32_fp8_fp8(
                    a[m], b[n], acc[m][n], 0, 0, 0);
    }

    float s0 = 0.f, s1 = 0.f, ps = 0.f, pc = 0.f;
    #pragma unroll
    for (int n = 0; n < 4; ++n) {
        int gj = colbase + n * 16 + lrow;
        int labj = labels[gj];
        int bj   = biases[gj];
        #pragma unroll
        for (int m = 0; m < 4; ++m) {
            #pragma unroll
            for (int e = 0; e < 4; ++e) {
                int gi = rowbase + m * 16 + kgrp * 4 + e;
                if (gi > gj) {
                    float g = acc[m][n][e];
                    g = fminf(fmaxf(g, -1.f), 1.f);
                    int bi = biases[gi];
                    if (bi == bj) {
                        if (bi == 0) s0 += g; else s1 += g;
                    } else if (labels[gi] == labj && bi < bj) {
                        ps += 1.f + g;
                        pc += 1.f;
                    }
                }
            }
        }
    }
    #pragma unroll
    for (int off = 32; off > 0; off >>= 1) {
        s0 += __shfl_down(s0, off);
        s1 += __shfl_down(s1, off);
        ps += __shfl_down(ps, off);
        pc += __shfl_down(pc, off);
    }
    if (lane == 0) {
        atomicAdd(&accbuf[0], s0);
        atomicAdd(&accbuf[1], s1);
        atomicAdd(&accbuf[2], ps);
        atomicAdd(&accbuf[3], pc);
    }
}

// ---------------------------------------------------------------------------
// Cross-entropy + bias-class counts.  accbuf: [4]=CE sum [5]=n0 [6]=n1
// ---------------------------------------------------------------------------
__global__ __launch_bounds__(256)
void ce_count_kernel(const float* __restrict__ logits,
                     const int* __restrict__ labels,
                     const int* __restrict__ biases,
                     float* __restrict__ accbuf,
                     int N, int C)
{
    int i = blockIdx.x * blockDim.x + threadIdx.x;
    float loss = 0.f, c0 = 0.f, c1 = 0.f;
    if (i < N) {
        const float* row = logits + (size_t)i * C;
        float mx = -INFINITY;
        for (int k = 0; k < C; ++k) mx = fmaxf(mx, row[k]);
        float s = 0.f;
        for (int k = 0; k < C; ++k) s += expf(row[k] - mx);
        loss = mx + logf(s) - row[labels[i]];
        if (biases[i] == 0) c0 = 1.f; else c1 = 1.f;
    }
    #pragma unroll
    for (int off = 32; off > 0; off >>= 1) {
        loss += __shfl_down(loss, off);
        c0   += __shfl_down(c0, off);
        c1   += __shfl_down(c1, off);
    }
    if ((threadIdx.x & 63) == 0) {
        atomicAdd(&accbuf[4], loss);
        atomicAdd(&accbuf[5], c0);
        atomicAdd(&accbuf[6], c1);
    }
}

// ---------------------------------------------------------------------------
// Finalize
// ---------------------------------------------------------------------------
__global__ void finalize_kernel(const float* __restrict__ accbuf,
                                float* __restrict__ out, int N)
{
    float S0 = accbuf[0], S1 = accbuf[1], ps = accbuf[2], pc = accbuf[3];
    float ce = accbuf[4], n0 = accbuf[5], n1 = accbuf[6];
    float Mo = 0.5f * (n0 * (n0 - 1.f) + n1 * (n1 - 1.f));
    float Ro = (Mo > 0.f) ? (fabsf(S0) + fabsf(S1)) / Mo : 0.f;
    float Rp = (pc > 0.f) ? 1.f + (-0.5f * ps) / pc : 0.f;
    out[0] = ce / (float)N;
    out[1] = Ro + Rp;   // ALPHA=BETA=1
}

extern "C" void kernel_launch(void* const* d_in, const int* in_sizes, int n_in,
                              void* d_out, int out_size, void* d_ws, size_t ws_size,
                              hipStream_t stream)
{
    const float* logits = (const float*)d_in[0];
    const int*   labels = (const int*)d_in[1];
    const int*   biases = (const int*)d_in[2];
    const float* feats  = (const float*)d_in[3];

    int N = in_sizes[1];              // 4096
    int C = in_sizes[0] / N;          // 10
    int D = in_sizes[3] / N;          // 2048

    float* accbuf = (float*)d_ws;
    hipMemsetAsync(accbuf, 0, 8 * sizeof(float), stream);

    unsigned char* fb = (unsigned char*)d_ws + 256;   // 8 MB fp8 buffer
    int nc = N * (D >> 3);
    convert_frag8_kernel<<<(nc + 255) / 256, 256, 0, stream>>>(feats, fb, N, D);

    if (N == 4096) {
        gram_band8_kernel<<<528, 256, 0, stream>>>(fb, labels, biases, accbuf,
                                                   N, D);
    } else {
        int nt = N / 64;
        int T  = nt * (nt + 1) / 2;
        gram_frag8_kernel<<<T / 4, 256, 0, stream>>>(fb, labels, biases,
                                                     accbuf, N, D);
    }
    ce_count_kernel<<<(N + 255) / 256, 256, 0, stream>>>(logits, labels, biases,
                                                         accbuf, N, C);
    finalize_kernel<<<1, 1, 0, stream>>>(accbuf, (float*)d_out, N);
}

// Round 9
// 162.235 us; speedup vs baseline: 2.9997x; 1.1648x over previous
//
#include <hip/hip_runtime.h>
#include <hip/hip_bf16.h>

// Types
typedef float f32x4 __attribute__((ext_vector_type(4)));
typedef unsigned int uint4v __attribute__((ext_vector_type(4)));
typedef unsigned long u64x2 __attribute__((ext_vector_type(2)));

// ---------------------------------------------------------------------------
// Pre-pass: feats f32 -> fp8 e4m3 in PAIR-INTERLEAVED FRAGMENT-MAJOR layout.
// 16B unit u: lane = u&63 (lrow=lane&15, kgrp=lane>>4), Kbp = (u>>6)%(D/64),
// R = (u>>6)/(D/64).  Unit bytes [0:8) = fp8 chunk for K-step 2*Kbp
// (k = Kbp*64 + kgrp*8), bytes [8:16) = chunk for K-step 2*Kbp+1 (k+32).
// A wave's TWO consecutive K-step fragments = ONE coalesced 1KB dwordx4 load.
// ---------------------------------------------------------------------------
__global__ __launch_bounds__(256)
void convert_pair8_kernel(const float* __restrict__ in,
                          unsigned char* __restrict__ out,
                          int N, int D)
{
    int u = blockIdx.x * blockDim.x + threadIdx.x;
    int nKbp = D >> 6;
    int nu = (N >> 4) * nKbp * 64;
    if (u >= nu) return;
    int lane = u & 63;
    int q    = u >> 6;
    int Kbp  = q % nKbp;
    int R    = q / nKbp;
    int lrow = lane & 15, kgrp = lane >> 4;
    int row  = R * 16 + lrow;
    int k0   = Kbp * 64 + kgrp * 8;
    const float* s = in + (size_t)row * D + k0;
    f32x4 a0 = *(const f32x4*)s;
    f32x4 a1 = *(const f32x4*)(s + 4);
    f32x4 b0 = *(const f32x4*)(s + 32);
    f32x4 b1 = *(const f32x4*)(s + 36);
    unsigned w0 = __builtin_amdgcn_cvt_pk_fp8_f32(a0[0], a0[1], 0, 0);
    w0 = __builtin_amdgcn_cvt_pk_fp8_f32(a0[2], a0[3], w0, 1);
    unsigned w1 = __builtin_amdgcn_cvt_pk_fp8_f32(a1[0], a1[1], 0, 0);
    w1 = __builtin_amdgcn_cvt_pk_fp8_f32(a1[2], a1[3], w1, 1);
    unsigned w2 = __builtin_amdgcn_cvt_pk_fp8_f32(b0[0], b0[1], 0, 0);
    w2 = __builtin_amdgcn_cvt_pk_fp8_f32(b0[2], b0[3], w2, 1);
    unsigned w3 = __builtin_amdgcn_cvt_pk_fp8_f32(b1[0], b1[1], 0, 0);
    w3 = __builtin_amdgcn_cvt_pk_fp8_f32(b1[2], b1[3], w3, 1);
    uint4v v = {w0, w1, w2, w3};
    *(uint4v*)(out + (size_t)u * 16) = v;
}

// ---- per-wave 64x64 tile with explicit 2-deep register pipeline ----
#define MM(Am, Bn, m, n)                                                      \
  acc[m][n] = __builtin_amdgcn_mfma_f32_16x16x32_fp8_fp8(                     \
      (long)(Am)[0], (long)(Bn)[0], acc[m][n], 0, 0, 0);                      \
  acc[m][n] = __builtin_amdgcn_mfma_f32_16x16x32_fp8_fp8(                     \
      (long)(Am)[1], (long)(Bn)[1], acc[m][n], 0, 0, 0);

#define MFMAP(A0,A1,A2,A3,B0,B1,B2,B3) do {                                   \
  MM(A0,B0,0,0) MM(A0,B1,0,1) MM(A0,B2,0,2) MM(A0,B3,0,3)                     \
  MM(A1,B0,1,0) MM(A1,B1,1,1) MM(A1,B2,1,2) MM(A1,B3,1,3)                     \
  MM(A2,B0,2,0) MM(A2,B1,2,1) MM(A2,B2,2,2) MM(A2,B3,2,3)                     \
  MM(A3,B0,3,0) MM(A3,B1,3,1) MM(A3,B2,3,2) MM(A3,B3,3,3) } while (0)

#define LOADP(K, A0,A1,A2,A3,B0,B1,B2,B3) do {                                \
  size_t o_ = (size_t)(K) * 64 + lane;                                        \
  A0 = pa0[o_]; A1 = pa1[o_]; A2 = pa2[o_]; A3 = pa3[o_];                     \
  B0 = pb0[o_]; B1 = pb1[o_]; B2 = pb2[o_]; B3 = pb3[o_]; } while (0)

__device__ __forceinline__ void gram_tile_pair8(
    const u64x2* __restrict__ fbv,
    const int* __restrict__ labels,
    const int* __restrict__ biases,
    float* __restrict__ accbuf,
    int rowbase, int colbase, int nKbp, int lane)
{
    int lrow = lane & 15;
    int kgrp = lane >> 4;
    int Ra = rowbase >> 4;
    int Rb = colbase >> 4;
    const u64x2* pa0 = fbv + (size_t)(Ra + 0) * nKbp * 64;
    const u64x2* pa1 = fbv + (size_t)(Ra + 1) * nKbp * 64;
    const u64x2* pa2 = fbv + (size_t)(Ra + 2) * nKbp * 64;
    const u64x2* pa3 = fbv + (size_t)(Ra + 3) * nKbp * 64;
    const u64x2* pb0 = fbv + (size_t)(Rb + 0) * nKbp * 64;
    const u64x2* pb1 = fbv + (size_t)(Rb + 1) * nKbp * 64;
    const u64x2* pb2 = fbv + (size_t)(Rb + 2) * nKbp * 64;
    const u64x2* pb3 = fbv + (size_t)(Rb + 3) * nKbp * 64;

    f32x4 acc[4][4] = {};
    u64x2 pA0, pA1, pA2, pA3, pB0, pB1, pB2, pB3;
    u64x2 qA0, qA1, qA2, qA3, qB0, qB1, qB2, qB3;

    LOADP(0, pA0,pA1,pA2,pA3, pB0,pB1,pB2,pB3);
    for (int i = 0; i < nKbp; i += 2) {
        LOADP(i + 1, qA0,qA1,qA2,qA3, qB0,qB1,qB2,qB3);   // nKbp even: in-bounds
        MFMAP(pA0,pA1,pA2,pA3, pB0,pB1,pB2,pB3);
        if (i + 2 < nKbp)
            LOADP(i + 2, pA0,pA1,pA2,pA3, pB0,pB1,pB2,pB3);
        MFMAP(qA0,qA1,qA2,qA3, qB0,qB1,qB2,qB3);
    }

    // ---- epilogue: clip + masks + reduce ----
    // C/D layout: col = lane&15, row = (lane>>4)*4 + reg (verified R2-R8)
    float s0 = 0.f, s1 = 0.f, ps = 0.f, pc = 0.f;
    #pragma unroll
    for (int n = 0; n < 4; ++n) {
        int gj = colbase + n * 16 + lrow;
        int labj = labels[gj];
        int bj   = biases[gj];
        #pragma unroll
        for (int m = 0; m < 4; ++m) {
            #pragma unroll
            for (int e = 0; e < 4; ++e) {
                int gi = rowbase + m * 16 + kgrp * 4 + e;
                if (gi > gj) {
                    float g = acc[m][n][e];
                    g = fminf(fmaxf(g, -1.f), 1.f);
                    int bi = biases[gi];
                    if (bi == bj) {
                        if (bi == 0) s0 += g; else s1 += g;
                    } else if (labels[gi] == labj && bi < bj) {
                        ps += 1.f + g;
                        pc += 1.f;
                    }
                }
            }
        }
    }
    #pragma unroll
    for (int off = 32; off > 0; off >>= 1) {
        s0 += __shfl_down(s0, off);
        s1 += __shfl_down(s1, off);
        ps += __shfl_down(ps, off);
        pc += __shfl_down(pc, off);
    }
    if (lane == 0) {
        atomicAdd(&accbuf[0], s0);
        atomicAdd(&accbuf[1], s1);
        atomicAdd(&accbuf[2], ps);
        atomicAdd(&accbuf[3], pc);
    }
}

// ---------------------------------------------------------------------------
// Banded schedule (N==4096): 528 blocks; XCD x=b&7 owns half-bands x and
// 15-x (66 tiles each, A-rows L2-resident; verified R7/R8). Block = 128x128
// tile as 4 barrier-free 64x64 wave-quadrants.
// accbuf: [0]=S0 [1]=S1 [2]=ps [3]=pc
// ---------------------------------------------------------------------------
__global__ __launch_bounds__(256, 2)
void gram_band_pair8_kernel(const unsigned char* __restrict__ fb,
                            const int* __restrict__ labels,
                            const int* __restrict__ biases,
                            float* __restrict__ accbuf,
                            int N, int D)
{
    int nKbp = D >> 6;
    int wid  = threadIdx.x >> 6;
    int lane = threadIdx.x & 63;
    int wr   = wid >> 1;
    int wc   = wid & 1;

    int x = blockIdx.x & 7;
    int s = blockIdx.x >> 3;
    int r, c;
    int n0 = 4 * x + 3;
    if (s < n0) {
        if (s == n0 - 1)      { r = 2 * x + 1;       c = 2 * x + 1; }
        else                  { r = 2 * x + (s & 1); c = s >> 1;    }
    } else {
        int s1    = s - n0;
        int rows0 = 30 - 2 * x;
        if (s1 == 2 * (rows0 + 1)) { r = rows0 + 1;        c = rows0 + 1; }
        else                       { r = rows0 + (s1 & 1); c = s1 >> 1;   }
    }

    int rowbase = r * 128 + wr * 64;
    int colbase = c * 128 + wc * 64;

    gram_tile_pair8((const u64x2*)fb, labels, biases, accbuf,
                    rowbase, colbase, nKbp, lane);
}

// ---------------------------------------------------------------------------
// Generic fallback (any N%64==0): wave-autonomous 64x64 tiles
// ---------------------------------------------------------------------------
__global__ __launch_bounds__(256, 2)
void gram_frag_pair8_kernel(const unsigned char* __restrict__ fb,
                            const int* __restrict__ labels,
                            const int* __restrict__ biases,
                            float* __restrict__ accbuf,
                            int N, int D)
{
    int nKbp = D >> 6;
    int wid  = threadIdx.x >> 6;
    int lane = threadIdx.x & 63;

    int bid = blockIdx.x;
    int nwg = gridDim.x;
    if ((nwg & 7) == 0) bid = (bid & 7) * (nwg >> 3) + (bid >> 3);
    int t = bid * 4 + wid;

    int r = (int)((sqrtf(8.0f * (float)t + 1.0f) - 1.0f) * 0.5f);
    while ((r + 1) * (r + 2) / 2 <= t) ++r;
    while (r * (r + 1) / 2 > t) --r;
    int c = t - r * (r + 1) / 2;

    gram_tile_pair8((const u64x2*)fb, labels, biases, accbuf,
                    r * 64, c * 64, nKbp, lane);
}

// ---------------------------------------------------------------------------
// Cross-entropy + bias-class counts.  accbuf: [4]=CE sum [5]=n0 [6]=n1
// ---------------------------------------------------------------------------
__global__ __launch_bounds__(256)
void ce_count_kernel(const float* __restrict__ logits,
                     const int* __restrict__ labels,
                     const int* __restrict__ biases,
                     float* __restrict__ accbuf,
                     int N, int C)
{
    int i = blockIdx.x * blockDim.x + threadIdx.x;
    float loss = 0.f, c0 = 0.f, c1 = 0.f;
    if (i < N) {
        const float* row = logits + (size_t)i * C;
        float mx = -INFINITY;
        for (int k = 0; k < C; ++k) mx = fmaxf(mx, row[k]);
        float s = 0.f;
        for (int k = 0; k < C; ++k) s += expf(row[k] - mx);
        loss = mx + logf(s) - row[labels[i]];
        if (biases[i] == 0) c0 = 1.f; else c1 = 1.f;
    }
    #pragma unroll
    for (int off = 32; off > 0; off >>= 1) {
        loss += __shfl_down(loss, off);
        c0   += __shfl_down(c0, off);
        c1   += __shfl_down(c1, off);
    }
    if ((threadIdx.x & 63) == 0) {
        atomicAdd(&accbuf[4], loss);
        atomicAdd(&accbuf[5], c0);
        atomicAdd(&accbuf[6], c1);
    }
}

// ---------------------------------------------------------------------------
// Finalize
// ---------------------------------------------------------------------------
__global__ void finalize_kernel(const float* __restrict__ accbuf,
                                float* __restrict__ out, int N)
{
    float S0 = accbuf[0], S1 = accbuf[1], ps = accbuf[2], pc = accbuf[3];
    float ce = accbuf[4], n0 = accbuf[5], n1 = accbuf[6];
    float Mo = 0.5f * (n0 * (n0 - 1.f) + n1 * (n1 - 1.f));
    float Ro = (Mo > 0.f) ? (fabsf(S0) + fabsf(S1)) / Mo : 0.f;
    float Rp = (pc > 0.f) ? 1.f + (-0.5f * ps) / pc : 0.f;
    out[0] = ce / (float)N;
    out[1] = Ro + Rp;   // ALPHA=BETA=1
}

extern "C" void kernel_launch(void* const* d_in, const int* in_sizes, int n_in,
                              void* d_out, int out_size, void* d_ws, size_t ws_size,
                              hipStream_t stream)
{
    const float* logits = (const float*)d_in[0];
    const int*   labels = (const int*)d_in[1];
    const int*   biases = (const int*)d_in[2];
    const float* feats  = (const float*)d_in[3];

    int N = in_sizes[1];              // 4096
    int C = in_sizes[0] / N;          // 10
    int D = in_sizes[3] / N;          // 2048

    float* accbuf = (float*)d_ws;
    hipMemsetAsync(accbuf, 0, 8 * sizeof(float), stream);

    unsigned char* fb = (unsigned char*)d_ws + 256;   // 8 MB fp8 buffer
    int nu = (N >> 4) * (D >> 6) * 64;
    convert_pair8_kernel<<<(nu + 255) / 256, 256, 0, stream>>>(feats, fb, N, D);

    if (N == 4096) {
        gram_band_pair8_kernel<<<528, 256, 0, stream>>>(fb, labels, biases,
                                                        accbuf, N, D);
    } else {
        int nt = N / 64;
        int T  = nt * (nt + 1) / 2;
        gram_frag_pair8_kernel<<<T / 4, 256, 0, stream>>>(fb, labels, biases,
                                                          accbuf, N, D);
    }
    ce_count_kernel<<<(N + 255) / 256, 256, 0, stream>>>(logits, labels, biases,
                                                         accbuf, N, C);
    finalize_kernel<<<1, 1, 0, stream>>>(accbuf, (float*)d_out, N);
}